// Round 6
// baseline (467.928 us; speedup 1.0000x reference)
//
#include <hip/hip_runtime.h>
#include <hip/hip_bf16.h>
#include <stdint.h>

// AttentionNet: h = tanh(att@Wh^T + ref@Wv^T); s = h@Ws^T; w = softmax(s); out = w@att
// S=131072, D=K=512.  Single HBM pass over att (268 MB) via fused unnormalized-softmax.
//
// R6 = R5 + chunked A-pack (the only change).
//  Diagnosis: R5's WRITE_SIZE 21.5MB = ~18 dwords/thread spilled; the fully-unrolled
//  A-pack lets the scheduler hoist all 64 16B-loads (~256 transient VGPRs) on top of
//  the growing afrag -> allocator spills afrag -> scratch reloads in the MFMA loop's
//  serial path.  Fix: sched_barrier(0) fences cap in-flight A-loads at 16 (64 VGPRs).
//  R5's paired-tile counted-vmcnt pipeline (32 MFMA/barrier) kept verbatim.

#define D_DIM 512
#define BM 128           // rows per block (4 waves x 32 rows)

typedef __attribute__((ext_vector_type(8))) short short8;
typedef __attribute__((ext_vector_type(4))) float f32x4;

// ws layout (floats): [0,512) bias; [512,1024) out_unnorm; [1024] Z; [1025] m_bound
// bytes [8192, 8192+524288): Bpk = bf16 Wh, fragment-ordered, 64 tiles x 8KB
#define WS_BIAS 0
#define WS_OUT  512
#define WS_Z    1024
#define WS_MB   1025
#define BPK_FLOAT_OFF 2048

#define WAITV4 asm volatile("s_waitcnt vmcnt(4)" ::: "memory")
#define WAITV0 asm volatile("s_waitcnt vmcnt(0)" ::: "memory")

__device__ __forceinline__ uint32_t pack2(float a, float b) {
    // lowers to v_cvt_pk_bf16_f32 (RNE)
    union { __hip_bfloat162 h; uint32_t u; } cv;
    cv.h = __float22bfloat162_rn(make_float2(a, b));
    return cv.u;
}
__device__ __forceinline__ float bf2f(unsigned short b) {
    return __uint_as_float(((uint32_t)b) << 16);
}
__device__ __forceinline__ float fast_tanh(float x) {
    float a = fabsf(x);
    float e = __expf(2.0f * a);
    float t = 1.0f - 2.0f / (e + 1.0f);     // e==inf -> t=1 (graceful saturation)
    return copysignf(t, x);
}
// VALU-pipe butterfly sum across the 16-lane groups (no LDS traffic)
template<int CTRL>
__device__ __forceinline__ float dpp_add(float v) {
    int i = __builtin_amdgcn_mov_dpp(__float_as_int(v), CTRL, 0xf, 0xf, true);
    return v + __int_as_float(i);
}
__device__ __forceinline__ float reduce16(float v) {
    v = dpp_add<0xB1>(v);    // quad_perm [1,0,3,2]  (xor 1)
    v = dpp_add<0x4E>(v);    // quad_perm [2,3,0,1]  (xor 2)
    v = dpp_add<0x141>(v);   // row_half_mirror      (completes 8-lane sum)
    v = dpp_add<0x140>(v);   // row_mirror           (completes 16-lane sum)
    return v;
}
// async global->LDS, 16B per lane; lds dst is wave-uniform base (+lane*16 by HW)
__device__ __forceinline__ void gl_lds16(const unsigned short* g, unsigned short* l) {
    __builtin_amdgcn_global_load_lds(
        (const __attribute__((address_space(1))) void*)g,
        (__attribute__((address_space(3))) void*)l, 16, 0, 0);
}

// K0: bias[d] = sum_k ref[k]*Wv[d,k]; m_bound = sum|Ws|; zero Z/out accumulators.
__global__ void k0_prep(const float* __restrict__ ref, const float* __restrict__ Wv,
                        const float* __restrict__ Ws, float* __restrict__ wsb) {
    __shared__ float red[256];
    const int tid = threadIdx.x;
    const int w = tid >> 6, l = tid & 63;
    const int d = blockIdx.x * 4 + w;          // 128 blocks x 4 waves = 512 outputs
    const f32x4* rp = (const f32x4*)ref;
    const f32x4* vp = (const f32x4*)(Wv + (size_t)d * D_DIM);
    f32x4 r0 = rp[2 * l], r1 = rp[2 * l + 1];
    f32x4 v0 = vp[2 * l], v1 = vp[2 * l + 1];
    float acc = r0[0]*v0[0] + r0[1]*v0[1] + r0[2]*v0[2] + r0[3]*v0[3]
              + r1[0]*v1[0] + r1[1]*v1[1] + r1[2]*v1[2] + r1[3]*v1[3];
    #pragma unroll
    for (int m = 1; m < 64; m <<= 1) acc += __shfl_xor(acc, m, 64);
    if (l == 0) wsb[WS_BIAS + d] = acc;

    if (blockIdx.x == 0) {
        wsb[WS_OUT + tid] = 0.0f;
        wsb[WS_OUT + 256 + tid] = 0.0f;
        if (tid == 0) wsb[WS_Z] = 0.0f;
        red[tid] = fabsf(Ws[tid]) + fabsf(Ws[tid + 256]);
        __syncthreads();
        for (int off = 128; off > 0; off >>= 1) {
            if (tid < off) red[tid] += red[tid + off];
            __syncthreads();
        }
        if (tid == 0) wsb[WS_MB] = red[0];
    }
}

// KB: Wh fp32 -> bf16, fragment-ordered.  chunk c (16B) at byte c*16 of tile t holds
// Wh[n = g*128 + ns*16 + l15][k = kc*32 + q*8 + j], j=0..7, where t = g*16+kc,
// q=c>>7, ns=(c>>4)&7, l15=c&15.  k1 lane (l15,q) reads chunk q*128+ns*16+l15 per ns.
__global__ void kB_pack(const float* __restrict__ Wh, unsigned short* __restrict__ bpk) {
    const int t = blockIdx.x;            // tile id: g = t>>4, kc = t&15
    const int g = t >> 4, kc = t & 15;
    #pragma unroll
    for (int h = 0; h < 2; ++h) {
        const int c = threadIdx.x + 256 * h;        // chunk in [0,512)
        const int q = c >> 7, ns = (c >> 4) & 7, l15 = c & 15;
        const int n = g * 128 + ns * 16 + l15;
        const int k0 = kc * 32 + q * 8;
        const f32x4* wp = (const f32x4*)(Wh + (size_t)n * D_DIM + k0);
        f32x4 x0 = wp[0], x1 = wp[1];
        union { short8 s; uint32_t u[4]; } pk;
        pk.u[0] = pack2(x0[0], x0[1]);
        pk.u[1] = pack2(x0[2], x0[3]);
        pk.u[2] = pack2(x1[0], x1[1]);
        pk.u[3] = pack2(x1[2], x1[3]);
        *(short8*)(bpk + (size_t)t * 4096 + (size_t)c * 8) = pk.s;
    }
}

// K1: per block of 128 rows: GEMM(tanh, Ws-dot) -> e=exp(score-m) -> fused weighted sum.
__launch_bounds__(256, 2)
__global__ void k1_main(const float* __restrict__ att,
                        const float* __restrict__ Ws,
                        const unsigned short* __restrict__ bpk, float* __restrict__ wsb) {
    __shared__ __align__(16) unsigned short Bt[6][4096];  // 6 x 8KB tiles = 3 pairs
    __shared__ float bias_s[512];
    __shared__ float wss_s[512];
    __shared__ float e_s[BM];
    __shared__ float out_s[512];

    const int tid = threadIdx.x;
    const int w   = tid >> 6;      // wave 0..3, owns rows [32w, 32w+32)
    const int l   = tid & 63;
    const int l15 = l & 15;
    const int q   = l >> 4;
    const int row0 = blockIdx.x * BM;

    const unsigned short* bpk_w = bpk + (size_t)w * 1024 + (size_t)l * 8;

    // prologue: pair 0 (tiles 0,1 -> buffers 0,1), issued before A-pack
    #pragma unroll
    for (int t = 0; t < 2; ++t) {
        const unsigned short* s = bpk_w + (size_t)t * 4096;
        gl_lds16(s, &Bt[t][w * 1024]);
        gl_lds16(s + 512, &Bt[t][w * 1024 + 512]);
    }

    for (int i = tid; i < 512; i += 256) {
        bias_s[i] = wsb[WS_BIAS + i];
        wss_s[i]  = Ws[i];
        out_s[i]  = 0.0f;
    }
    const float mb = wsb[WS_MB];

    // ---- phase 1: att rows -> bf16 MFMA A-fragments in registers (read att ONCE) ----
    // A-frag layout (16x16x32): lane holds A[m=l15][k = q*8 + j], j=0..7
    // CHUNKED: sched_barrier(0) fences cap in-flight loads at 16 (64 transient VGPRs)
    // so the allocator never spills afrag to scratch (R5: 18 dwords spilled, reloaded
    // inside the MFMA loop).
    short8 afrag[2][16];
    #pragma unroll
    for (int t = 0; t < 2; ++t) {
        const int row = row0 + 32 * w + 16 * t + l15;
        const f32x4* ap = (const f32x4*)(att + (size_t)row * D_DIM + q * 8);
        #pragma unroll
        for (int kh = 0; kh < 2; ++kh) {          // 2 chunks of 8 kc per t
            #pragma unroll
            for (int kc8 = 0; kc8 < 8; ++kc8) {
                const int kc = kh * 8 + kc8;      // compile-time constant (static idx)
                f32x4 x0 = ap[kc * 8];
                f32x4 x1 = ap[kc * 8 + 1];
                union { short8 s; uint32_t u[4]; } af;
                af.u[0] = pack2(x0[0], x0[1]);
                af.u[1] = pack2(x0[2], x0[3]);
                af.u[2] = pack2(x1[0], x1[1]);
                af.u[3] = pack2(x1[2], x1[3]);
                afrag[t][kc] = af.s;
            }
            __builtin_amdgcn_sched_barrier(0);    // fence: next chunk's loads stay below
        }
    }

    // pair 1 (tiles 2,3 -> buffers 2,3).  A-pack loads above are all consumed, so
    // entering the loop the outstanding VMEM queue is at most {pair0, pair1}.
    #pragma unroll
    for (int t = 2; t < 4; ++t) {
        const unsigned short* s = bpk_w + (size_t)t * 4096;
        gl_lds16(s, &Bt[t][w * 1024]);
        gl_lds16(s + 512, &Bt[t][w * 1024 + 512]);
    }

    f32x4 acc[2][8];
    #pragma unroll
    for (int t = 0; t < 2; ++t)
        #pragma unroll
        for (int n = 0; n < 8; ++n) acc[t][n] = (f32x4){0.f, 0.f, 0.f, 0.f};
    float sc[8] = {0.f, 0.f, 0.f, 0.f, 0.f, 0.f, 0.f, 0.f};

    int bcur = 0;                              // buffer base of current pair (0/2/4)
    for (int g = 0; g < 4; ++g) {              // 4 N-groups of 128; tiles t = g*16+kc
        #pragma unroll
        for (int kp = 0; kp < 8; ++kp) {       // pair kp: tiles kc=2kp, 2kp+1
            // entering pair p: outstanding = {p, p+1} (8 ops); vmcnt(4) lands pair p.
            if (g == 3 && kp == 7) WAITV0; else WAITV4;
            __builtin_amdgcn_sched_barrier(0);
            __builtin_amdgcn_s_barrier();      // all waves' pair-p loads landed
            __builtin_amdgcn_sched_barrier(0);
            // issue pair p+2 into pair p-1's buffers (readers crossed the barrier)
            {
                const int tn = g * 16 + kp * 2 + 4;
                if (tn < 64) {
                    const int bpre = (bcur + 4 == 6) ? 0 : ((bcur + 4 == 8) ? 2 : 4);
                    #pragma unroll
                    for (int i = 0; i < 2; ++i) {
                        const unsigned short* s = bpk_w + (size_t)(tn + i) * 4096;
                        unsigned short* dld = &Bt[bpre + i][w * 1024];
                        gl_lds16(s, dld);
                        gl_lds16(s + 512, dld + 512);
                    }
                }
            }
            __builtin_amdgcn_s_setprio(1);
            #pragma unroll
            for (int i = 0; i < 2; ++i) {      // 2 tiles x 16 MFMA = 32 MFMA per barrier
                const unsigned short* bb = &Bt[0][0] + (size_t)(bcur + i) * 4096;
                #pragma unroll
                for (int ns = 0; ns < 8; ++ns) {
                    short8 bfr = *(const short8*)(bb + (q * 128 + ns * 16 + l15) * 8);
                    acc[0][ns] = __builtin_amdgcn_mfma_f32_16x16x32_bf16(afrag[0][kp * 2 + i], bfr, acc[0][ns], 0, 0, 0);
                    acc[1][ns] = __builtin_amdgcn_mfma_f32_16x16x32_bf16(afrag[1][kp * 2 + i], bfr, acc[1][ns], 0, 0, 0);
                }
            }
            __builtin_amdgcn_s_setprio(0);
            bcur = (bcur + 2 == 6) ? 0 : bcur + 2;
        }
        // group epilogue: h=tanh(hpre+bias), partial score += h*Ws  (C/D: col=l15, row=q*4+r)
        #pragma unroll
        for (int t = 0; t < 2; ++t) {
            #pragma unroll
            for (int ns = 0; ns < 8; ++ns) {
                const int c = g * 128 + ns * 16 + l15;
                const float bc = bias_s[c];
                const float wc = wss_s[c];
                f32x4 a = acc[t][ns];
                #pragma unroll
                for (int r = 0; r < 4; ++r)
                    sc[t * 4 + r] += fast_tanh(a[r] + bc) * wc;
                acc[t][ns] = (f32x4){0.f, 0.f, 0.f, 0.f};
            }
        }
    }

    // reduce scores across the 16 column-lanes; all lanes end with the row sums
    #pragma unroll
    for (int i = 0; i < 8; ++i) sc[i] = reduce16(sc[i]);

    if (l15 == 0) {
        #pragma unroll
        for (int t = 0; t < 2; ++t)
            #pragma unroll
            for (int r = 0; r < 4; ++r)
                e_s[32 * w + 16 * t + q * 4 + r] = __expf(sc[t * 4 + r] - mb);
    }
    __syncthreads();

    // Z: block partial of sum(e) -> global atomic
    if (w == 0) {
        float z = e_s[l] + e_s[l + 64];
        #pragma unroll
        for (int m = 1; m < 64; m <<= 1) z += __shfl_xor(z, m, 64);
        if (l == 0) atomicAdd(&wsb[WS_Z], z);
    }

    // phase 4: out_part[k] = sum_rows e[row]*att_bf16[row][k] from register-resident A
    const float el0 = e_s[32 * w + l15];
    const float el1 = e_s[32 * w + 16 + l15];
    #pragma unroll
    for (int kc = 0; kc < 16; ++kc) {
        float o[8];
        #pragma unroll
        for (int j = 0; j < 8; ++j) {
            o[j] = el0 * bf2f((unsigned short)afrag[0][kc][j])
                 + el1 * bf2f((unsigned short)afrag[1][kc][j]);
            o[j] = reduce16(o[j]);
        }
        if (l15 == 0) {
            #pragma unroll
            for (int j = 0; j < 8; ++j)
                atomicAdd(&out_s[kc * 32 + q * 8 + j], o[j]);
        }
    }
    __syncthreads();
    for (int i = tid; i < 512; i += 256)
        atomicAdd(&wsb[WS_OUT + i], out_s[i]);
}

// K2: normalize
__global__ void k2_fin(const float* __restrict__ wsb, float* __restrict__ out) {
    const float z = wsb[WS_Z];
    out[threadIdx.x] = wsb[WS_OUT + threadIdx.x] / z;
}

extern "C" void kernel_launch(void* const* d_in, const int* in_sizes, int n_in,
                              void* d_out, int out_size, void* d_ws, size_t ws_size,
                              hipStream_t stream) {
    const float* att = (const float*)d_in[0];   // [131072, 512]
    const float* ref = (const float*)d_in[1];   // [512]
    const float* Wh  = (const float*)d_in[2];   // [512, 512]
    const float* Wv  = (const float*)d_in[3];   // [512, 512]
    const float* Ws  = (const float*)d_in[4];   // [512]
    float* out = (float*)d_out;                 // [512]
    float* wsb = (float*)d_ws;                  // 8 KB header + 512 KB Bpk

    unsigned short* bpk = (unsigned short*)(wsb + BPK_FLOAT_OFF);

    hipLaunchKernelGGL(k0_prep, dim3(128), dim3(256), 0, stream, ref, Wv, Ws, wsb);
    hipLaunchKernelGGL(kB_pack, dim3(64), dim3(256), 0, stream, Wh, bpk);
    hipLaunchKernelGGL(k1_main, dim3(131072 / BM), dim3(256), 0, stream, att, Ws, bpk, wsb);
    hipLaunchKernelGGL(k2_fin, dim3(1), dim3(512), 0, stream, wsb, out);
}

// Round 7
// 459.253 us; speedup vs baseline: 1.0189x; 1.0189x over previous
//
#include <hip/hip_runtime.h>
#include <hip/hip_bf16.h>
#include <stdint.h>

// AttentionNet: h = tanh(att@Wh^T + ref@Wv^T); s = h@Ws^T; w = softmax(s); out = w@att
// S=131072, D=K=512.  Single HBM pass over att (268 MB) via fused unnormalized-softmax.
//
// R7: spill kill + quad-tile phases.
//  Diagnosis (R6): spill is steady-state - compiler hoists all 16 ds_read_b128 per
//  pair (64 live bfr VGPRs) on top of afrag(128)+acc(64) -> ~19 dwords spilled,
//  reloaded in the GEMM serial path (WRITE_SIZE 21.5MB vs 2.5 expected).
//  Fix 1: MFMA cluster in sub-chunks {4 ds_read; 8 MFMA; sched_barrier(0)} -> max
//         16 live bfr VGPRs -> total demand ~200 < 256, no spill.
//  Fix 2: 4 tiles per sync point (8 LDS tile-buffers = 2 quad-buffers, 2-deep
//         pipeline): 16 barriers (was 32), 64 MFMA/barrier, vmcnt(0) at phase entry
//         waits only on loads issued a full phase earlier (~free).

#define D_DIM 512
#define BM 128           // rows per block (4 waves x 32 rows)

typedef __attribute__((ext_vector_type(8))) short short8;
typedef __attribute__((ext_vector_type(4))) float f32x4;

// ws layout (floats): [0,512) bias; [512,1024) out_unnorm; [1024] Z; [1025] m_bound
// bytes [8192, 8192+524288): Bpk = bf16 Wh, fragment-ordered, 64 tiles x 8KB
#define WS_BIAS 0
#define WS_OUT  512
#define WS_Z    1024
#define WS_MB   1025
#define BPK_FLOAT_OFF 2048

#define WAITV0 asm volatile("s_waitcnt vmcnt(0)" ::: "memory")

__device__ __forceinline__ uint32_t pack2(float a, float b) {
    // lowers to v_cvt_pk_bf16_f32 (RNE)
    union { __hip_bfloat162 h; uint32_t u; } cv;
    cv.h = __float22bfloat162_rn(make_float2(a, b));
    return cv.u;
}
__device__ __forceinline__ float bf2f(unsigned short b) {
    return __uint_as_float(((uint32_t)b) << 16);
}
__device__ __forceinline__ float fast_tanh(float x) {
    float a = fabsf(x);
    float e = __expf(2.0f * a);
    float t = 1.0f - 2.0f / (e + 1.0f);     // e==inf -> t=1 (graceful saturation)
    return copysignf(t, x);
}
// VALU-pipe butterfly sum across the 16-lane groups (no LDS traffic)
template<int CTRL>
__device__ __forceinline__ float dpp_add(float v) {
    int i = __builtin_amdgcn_mov_dpp(__float_as_int(v), CTRL, 0xf, 0xf, true);
    return v + __int_as_float(i);
}
__device__ __forceinline__ float reduce16(float v) {
    v = dpp_add<0xB1>(v);    // quad_perm [1,0,3,2]  (xor 1)
    v = dpp_add<0x4E>(v);    // quad_perm [2,3,0,1]  (xor 2)
    v = dpp_add<0x141>(v);   // row_half_mirror      (completes 8-lane sum)
    v = dpp_add<0x140>(v);   // row_mirror           (completes 16-lane sum)
    return v;
}
// async global->LDS, 16B per lane; lds dst is wave-uniform base (+lane*16 by HW)
__device__ __forceinline__ void gl_lds16(const unsigned short* g, unsigned short* l) {
    __builtin_amdgcn_global_load_lds(
        (const __attribute__((address_space(1))) void*)g,
        (__attribute__((address_space(3))) void*)l, 16, 0, 0);
}

// K0: bias[d] = sum_k ref[k]*Wv[d,k]; m_bound = sum|Ws|; zero Z/out accumulators.
__global__ void k0_prep(const float* __restrict__ ref, const float* __restrict__ Wv,
                        const float* __restrict__ Ws, float* __restrict__ wsb) {
    __shared__ float red[256];
    const int tid = threadIdx.x;
    const int w = tid >> 6, l = tid & 63;
    const int d = blockIdx.x * 4 + w;          // 128 blocks x 4 waves = 512 outputs
    const f32x4* rp = (const f32x4*)ref;
    const f32x4* vp = (const f32x4*)(Wv + (size_t)d * D_DIM);
    f32x4 r0 = rp[2 * l], r1 = rp[2 * l + 1];
    f32x4 v0 = vp[2 * l], v1 = vp[2 * l + 1];
    float acc = r0[0]*v0[0] + r0[1]*v0[1] + r0[2]*v0[2] + r0[3]*v0[3]
              + r1[0]*v1[0] + r1[1]*v1[1] + r1[2]*v1[2] + r1[3]*v1[3];
    #pragma unroll
    for (int m = 1; m < 64; m <<= 1) acc += __shfl_xor(acc, m, 64);
    if (l == 0) wsb[WS_BIAS + d] = acc;

    if (blockIdx.x == 0) {
        wsb[WS_OUT + tid] = 0.0f;
        wsb[WS_OUT + 256 + tid] = 0.0f;
        if (tid == 0) wsb[WS_Z] = 0.0f;
        red[tid] = fabsf(Ws[tid]) + fabsf(Ws[tid + 256]);
        __syncthreads();
        for (int off = 128; off > 0; off >>= 1) {
            if (tid < off) red[tid] += red[tid + off];
            __syncthreads();
        }
        if (tid == 0) wsb[WS_MB] = red[0];
    }
}

// KB: Wh fp32 -> bf16, fragment-ordered.  chunk c (16B) at byte c*16 of tile t holds
// Wh[n = g*128 + ns*16 + l15][k = kc*32 + q*8 + j], j=0..7, where t = g*16+kc,
// q=c>>7, ns=(c>>4)&7, l15=c&15.  k1 lane (l15,q) reads chunk q*128+ns*16+l15 per ns.
__global__ void kB_pack(const float* __restrict__ Wh, unsigned short* __restrict__ bpk) {
    const int t = blockIdx.x;            // tile id: g = t>>4, kc = t&15
    const int g = t >> 4, kc = t & 15;
    #pragma unroll
    for (int h = 0; h < 2; ++h) {
        const int c = threadIdx.x + 256 * h;        // chunk in [0,512)
        const int q = c >> 7, ns = (c >> 4) & 7, l15 = c & 15;
        const int n = g * 128 + ns * 16 + l15;
        const int k0 = kc * 32 + q * 8;
        const f32x4* wp = (const f32x4*)(Wh + (size_t)n * D_DIM + k0);
        f32x4 x0 = wp[0], x1 = wp[1];
        union { short8 s; uint32_t u[4]; } pk;
        pk.u[0] = pack2(x0[0], x0[1]);
        pk.u[1] = pack2(x0[2], x0[3]);
        pk.u[2] = pack2(x1[0], x1[1]);
        pk.u[3] = pack2(x1[2], x1[3]);
        *(short8*)(bpk + (size_t)t * 4096 + (size_t)c * 8) = pk.s;
    }
}

// K1: per block of 128 rows: GEMM(tanh, Ws-dot) -> e=exp(score-m) -> fused weighted sum.
__launch_bounds__(256, 2)
__global__ void k1_main(const float* __restrict__ att,
                        const float* __restrict__ Ws,
                        const unsigned short* __restrict__ bpk, float* __restrict__ wsb) {
    __shared__ __align__(16) unsigned short Bt[8][4096];  // 2 quad-buffers (64 KB)
    __shared__ float bias_s[512];
    __shared__ float wss_s[512];
    __shared__ float e_s[BM];
    __shared__ float out_s[512];

    const int tid = threadIdx.x;
    const int w   = tid >> 6;      // wave 0..3, owns rows [32w, 32w+32)
    const int l   = tid & 63;
    const int l15 = l & 15;
    const int q   = l >> 4;
    const int row0 = blockIdx.x * BM;

    const unsigned short* bpk_w = bpk + (size_t)w * 1024 + (size_t)l * 8;

    // prologue: quad 0 (tiles 0-3 -> buffers 0-3), issued before A-pack
    #pragma unroll
    for (int t = 0; t < 4; ++t) {
        const unsigned short* s = bpk_w + (size_t)t * 4096;
        gl_lds16(s, &Bt[t][w * 1024]);
        gl_lds16(s + 512, &Bt[t][w * 1024 + 512]);
    }

    for (int i = tid; i < 512; i += 256) {
        bias_s[i] = wsb[WS_BIAS + i];
        wss_s[i]  = Ws[i];
        out_s[i]  = 0.0f;
    }
    const float mb = wsb[WS_MB];

    // ---- phase 1: att rows -> bf16 MFMA A-fragments in registers (read att ONCE) ----
    // A-frag layout (16x16x32): lane holds A[m=l15][k = q*8 + j], j=0..7
    short8 afrag[2][16];
    #pragma unroll
    for (int t = 0; t < 2; ++t) {
        const int row = row0 + 32 * w + 16 * t + l15;
        const f32x4* ap = (const f32x4*)(att + (size_t)row * D_DIM + q * 8);
        #pragma unroll
        for (int kh = 0; kh < 2; ++kh) {          // chunks cap in-flight A-loads
            #pragma unroll
            for (int kc8 = 0; kc8 < 8; ++kc8) {
                const int kc = kh * 8 + kc8;
                f32x4 x0 = ap[kc * 8];
                f32x4 x1 = ap[kc * 8 + 1];
                union { short8 s; uint32_t u[4]; } af;
                af.u[0] = pack2(x0[0], x0[1]);
                af.u[1] = pack2(x0[2], x0[3]);
                af.u[2] = pack2(x1[0], x1[1]);
                af.u[3] = pack2(x1[2], x1[3]);
                afrag[t][kc] = af.s;
            }
            __builtin_amdgcn_sched_barrier(0);
        }
    }

    f32x4 acc[2][8];
    #pragma unroll
    for (int t = 0; t < 2; ++t)
        #pragma unroll
        for (int n = 0; n < 8; ++n) acc[t][n] = (f32x4){0.f, 0.f, 0.f, 0.f};
    float sc[8] = {0.f, 0.f, 0.f, 0.f, 0.f, 0.f, 0.f, 0.f};

    for (int g = 0; g < 4; ++g) {              // 4 N-groups of 128; 16 quads total
        #pragma unroll
        for (int pq = 0; pq < 4; ++pq) {       // quad pq of group g; phase = g*4+pq
            // quad (g,pq) was issued one full phase ago (or in prologue) -> vmcnt(0)
            // waits only on long-landed loads.
            WAITV0;
            __builtin_amdgcn_sched_barrier(0);
            __builtin_amdgcn_s_barrier();      // all waves' quad loads landed
            __builtin_amdgcn_sched_barrier(0);
            // issue next quad into the other quad-buffer (its readers crossed barrier)
            {
                const int phn = g * 4 + pq + 1;
                if (phn < 16) {
                    const int bb = (phn & 1) * 4;
                    #pragma unroll
                    for (int i = 0; i < 4; ++i) {
                        const unsigned short* s = bpk_w + (size_t)(phn * 4 + i) * 4096;
                        unsigned short* dld = &Bt[bb + i][w * 1024];
                        gl_lds16(s, dld);
                        gl_lds16(s + 512, dld + 512);
                    }
                }
            }
            __builtin_amdgcn_s_setprio(1);
            const int bq = (pq & 1) * 4;       // current quad-buffer base
            #pragma unroll
            for (int i = 0; i < 4; ++i) {      // 4 tiles x 16 MFMA = 64 MFMA per barrier
                const int kc = pq * 4 + i;
                const unsigned short* bb2 = &Bt[bq + i][0];
                #pragma unroll
                for (int h = 0; h < 2; ++h) {  // sub-chunk: 4 ds_read + 8 MFMA
                    short8 bfr[4];
                    #pragma unroll
                    for (int n2 = 0; n2 < 4; ++n2) {
                        const int ns = h * 4 + n2;
                        bfr[n2] = *(const short8*)(bb2 + (q * 128 + ns * 16 + l15) * 8);
                    }
                    #pragma unroll
                    for (int n2 = 0; n2 < 4; ++n2) {
                        const int ns = h * 4 + n2;
                        acc[0][ns] = __builtin_amdgcn_mfma_f32_16x16x32_bf16(afrag[0][kc], bfr[n2], acc[0][ns], 0, 0, 0);
                        acc[1][ns] = __builtin_amdgcn_mfma_f32_16x16x32_bf16(afrag[1][kc], bfr[n2], acc[1][ns], 0, 0, 0);
                    }
                    __builtin_amdgcn_sched_barrier(0);  // cap live bfr at 16 VGPRs
                }
            }
            __builtin_amdgcn_s_setprio(0);
        }
        // group epilogue: h=tanh(hpre+bias), partial score += h*Ws  (C/D: col=l15, row=q*4+r)
        #pragma unroll
        for (int t = 0; t < 2; ++t) {
            #pragma unroll
            for (int ns = 0; ns < 8; ++ns) {
                const int c = g * 128 + ns * 16 + l15;
                const float bc = bias_s[c];
                const float wc = wss_s[c];
                f32x4 a = acc[t][ns];
                #pragma unroll
                for (int r = 0; r < 4; ++r)
                    sc[t * 4 + r] += fast_tanh(a[r] + bc) * wc;
                acc[t][ns] = (f32x4){0.f, 0.f, 0.f, 0.f};
            }
        }
    }

    // reduce scores across the 16 column-lanes; all lanes end with the row sums
    #pragma unroll
    for (int i = 0; i < 8; ++i) sc[i] = reduce16(sc[i]);

    if (l15 == 0) {
        #pragma unroll
        for (int t = 0; t < 2; ++t)
            #pragma unroll
            for (int r = 0; r < 4; ++r)
                e_s[32 * w + 16 * t + q * 4 + r] = __expf(sc[t * 4 + r] - mb);
    }
    __syncthreads();

    // Z: block partial of sum(e) -> global atomic
    if (w == 0) {
        float z = e_s[l] + e_s[l + 64];
        #pragma unroll
        for (int m = 1; m < 64; m <<= 1) z += __shfl_xor(z, m, 64);
        if (l == 0) atomicAdd(&wsb[WS_Z], z);
    }

    // phase 4: out_part[k] = sum_rows e[row]*att_bf16[row][k] from register-resident A
    const float el0 = e_s[32 * w + l15];
    const float el1 = e_s[32 * w + 16 + l15];
    #pragma unroll
    for (int kc = 0; kc < 16; ++kc) {
        float o[8];
        #pragma unroll
        for (int j = 0; j < 8; ++j) {
            o[j] = el0 * bf2f((unsigned short)afrag[0][kc][j])
                 + el1 * bf2f((unsigned short)afrag[1][kc][j]);
            o[j] = reduce16(o[j]);
        }
        if (l15 == 0) {
            #pragma unroll
            for (int j = 0; j < 8; ++j)
                atomicAdd(&out_s[kc * 32 + q * 8 + j], o[j]);
        }
    }
    __syncthreads();
    for (int i = tid; i < 512; i += 256)
        atomicAdd(&wsb[WS_OUT + i], out_s[i]);
}

// K2: normalize
__global__ void k2_fin(const float* __restrict__ wsb, float* __restrict__ out) {
    const float z = wsb[WS_Z];
    out[threadIdx.x] = wsb[WS_OUT + threadIdx.x] / z;
}

extern "C" void kernel_launch(void* const* d_in, const int* in_sizes, int n_in,
                              void* d_out, int out_size, void* d_ws, size_t ws_size,
                              hipStream_t stream) {
    const float* att = (const float*)d_in[0];   // [131072, 512]
    const float* ref = (const float*)d_in[1];   // [512]
    const float* Wh  = (const float*)d_in[2];   // [512, 512]
    const float* Wv  = (const float*)d_in[3];   // [512, 512]
    const float* Ws  = (const float*)d_in[4];   // [512]
    float* out = (float*)d_out;                 // [512]
    float* wsb = (float*)d_ws;                  // 8 KB header + 512 KB Bpk

    unsigned short* bpk = (unsigned short*)(wsb + BPK_FLOAT_OFF);

    hipLaunchKernelGGL(k0_prep, dim3(128), dim3(256), 0, stream, ref, Wv, Ws, wsb);
    hipLaunchKernelGGL(kB_pack, dim3(64), dim3(256), 0, stream, Wh, bpk);
    hipLaunchKernelGGL(k1_main, dim3(131072 / BM), dim3(256), 0, stream, att, Ws, bpk, wsb);
    hipLaunchKernelGGL(k2_fin, dim3(1), dim3(512), 0, stream, wsb, out);
}